// Round 15
// baseline (355.154 us; speedup 1.0000x reference)
//
#include <hip/hip_runtime.h>
#include <cstdint>
#include <cstddef>

typedef __attribute__((ext_vector_type(8))) short bf16x8;
typedef __attribute__((ext_vector_type(4))) float f32x4;
typedef __attribute__((ext_vector_type(4))) unsigned int u32x4;
typedef unsigned short u16;

#define LDS_STRIDE 1952                 /* A row: 1920 + 32 pad            */
#define XBUF_OFF   (36 * LDS_STRIDE)    /* 70272: x-region bf16, 4096 B    */
#define WL_OFF     (XBUF_OFF + 4096)    /* 74368: w1+b1 f32, 3584 B        */
#define SMEM_BYTES (WL_OFF + 3584)      /* 77952 <= 81920 -> 2 blocks/CU   */
#define OUT_CSTR   21952                /* 28*28*28                        */

__device__ __forceinline__ u16 f2bf(float f) {
    union { float f; unsigned u; } v; v.f = f;
    unsigned r = v.u + 0x7FFF + ((v.u >> 16) & 1);   // RNE
    return (u16)(r >> 16);
}

__device__ __forceinline__ float bf2f(u16 u) {
    union { unsigned u; float f; } v; v.u = ((unsigned)u) << 16;
    return v.f;
}

__device__ __forceinline__ void fma4(float4& a, float s, const float4& w) {
    a.x = fmaf(s, w.x, a.x);
    a.y = fmaf(s, w.y, a.y);
    a.z = fmaf(s, w.z, a.z);
    a.w = fmaf(s, w.w, a.w);
}

// ---------------- pack w2 fp32 DHWIO -> bf16 B-fragments ------------------
// wB[((tap*4 + nt)*64 + lane)*8 + j] = bf16(w2[tap][(lane>>4)*8 + j][nt*16 + (lane&15)])
__global__ __launch_bounds__(256) void pack_w2(
    const float* __restrict__ w2, u16* __restrict__ wB)
{
    const int tap = blockIdx.x;      // 0..26
    const int tid = threadIdx.x;
    const int nt = tid >> 6;
    const int l  = tid & 63;
    const int r = l & 15, q = l >> 4;
    u16* dst = wB + ((size_t)(tap * 4 + nt) * 64 + l) * 8;
#pragma unroll
    for (int j = 0; j < 8; ++j)
        dst[j] = f2bf(w2[(size_t)(tap * 32 + q * 8 + j) * 64 + nt * 16 + r]);
}

// ---------------- fused conv1+conv2 ---------------------------------------
// Grid 3136 = 49 tiles x 64 batches, XCD-swizzled. 512 thr (8 waves).
// PROLOGUE (fused conv1): stage x(8z x 8y x 32x) as bf16 + w1/b1 f32 into
// LDS; each thread computes 9 pair-units of h1 = relu(conv1(x)+b1) directly
// into the A-tile (36 rows x 1920 B, stride 1952) -- no h1 HBM round-trip,
// no separate conv1 launch. Halo rows recomputed per block (1.96x, VALU-pipe
// work hidden under MFMA of the desynced co-resident block).
// K-LOOP (r9/r14 best-measured config): wave wv=(zw,nh): z-plane z0+zw,
// N-half nh; 7 m-tiles x 2 n-frags; B from global 2 KB/wave/tap, 2-deep
// prefetch, counted vmcnt; no setprio; barrier-free.
__global__ __launch_bounds__(512, 4) void conv2_fused(
    const float* __restrict__ x, const float* __restrict__ w1,
    const float* __restrict__ b1, const u16* __restrict__ wB,
    const float* __restrict__ b2, float* __restrict__ out)
{
    __shared__ __align__(16) unsigned char smem[SMEM_BYTES];

    const int g   = gridDim.x;
    const int bid = blockIdx.x;
    const int lb  = (g % 8 == 0) ? ((bid & 7) * (g >> 3) + (bid >> 3)) : bid;

    const int t0  = lb % 49;
    const int b   = lb / 49;
    const int yg  = t0 % 7;
    const int zt  = t0 / 7;

    const int y0 = yg * 4, z0 = zt * 4;
    const int tid = threadIdx.x;
    const int wv  = tid >> 6;       // 0..7
    const int l   = tid & 63;
    const int zw  = wv >> 1;        // wave z offset 0..3
    const int nh  = wv & 1;         // wave N half
    const int r = l & 15, q = l >> 4;
    const int yl = r >> 2, xg = r & 3;

    // ==== prologue stage 1: x-region + weights -> LDS =====================
    // wave wv stages x plane z0+wv: 8y x 32x f32 -> bf16 (256 vals, 4/lane)
    {
        const float* xb = x + (size_t)b * 32768;
        const int yy  = l >> 3;          // 0..7
        const int xx4 = (l & 7) * 4;     // 0,4,..,28
        const float4 v = *reinterpret_cast<const float4*>(
            xb + ((size_t)(z0 + wv) * 32 + (y0 + yy)) * 32 + xx4);
        ushort4 s;
        s.x = f2bf(v.x); s.y = f2bf(v.y); s.z = f2bf(v.z); s.w = f2bf(v.w);
        *reinterpret_cast<ushort4*>(
            smem + XBUF_OFF + ((wv * 8 + yy) * 32 + xx4) * 2) = s;
    }
    // w1 (864 f32) + b1 (32 f32) -> LDS f32 at WL_OFF (224 thr x float4)
    if (tid < 224) {
        const int idx = tid * 4;
        float4 v;
        if (idx < 864) v = *reinterpret_cast<const float4*>(w1 + idx);
        else           v = *reinterpret_cast<const float4*>(b1 + (idx - 864));
        *reinterpret_cast<float4*>(smem + WL_OFF + idx * 4) = v;
    }
    __syncthreads();

    // ==== prologue stage 2: conv1 into A-tile =============================
    // pair-units: 36 rows x 15 x-pairs x 8 c4 = 4320; thread does 9 units
    {
        const float* wl = reinterpret_cast<const float*>(smem + WL_OFF);
        const u16* xbuf = reinterpret_cast<const u16*>(smem + XBUF_OFF);
#pragma unroll
        for (int i = 0; i < 9; ++i) {
            const int unit = tid + i * 512;
            if (unit < 4320) {
                const int row = unit / 120;
                const int rem = unit - row * 120;
                const int p   = rem >> 3;
                const int c4  = rem & 7;
                const int xx  = p * 2;
                const int rz  = row / 6;
                const int ry  = row - rz * 6;

                const float4 bias = *reinterpret_cast<const float4*>(
                    &wl[27 * 32 + c4 * 4]);
                float4 acc0 = bias, acc1 = bias;
#pragma unroll
                for (int kd = 0; kd < 3; ++kd) {
#pragma unroll
                    for (int kh = 0; kh < 3; ++kh) {
                        const ushort4 xr = *reinterpret_cast<const ushort4*>(
                            &xbuf[((rz + kd) * 8 + (ry + kh)) * 32 + xx]);
                        const float a0 = bf2f(xr.x), a1 = bf2f(xr.y);
                        const float a2 = bf2f(xr.z), a3 = bf2f(xr.w);
                        const int t = (kd * 3 + kh) * 3;
                        const float4 w0  = *reinterpret_cast<const float4*>(&wl[(t + 0) * 32 + c4 * 4]);
                        const float4 w1v = *reinterpret_cast<const float4*>(&wl[(t + 1) * 32 + c4 * 4]);
                        const float4 w2v = *reinterpret_cast<const float4*>(&wl[(t + 2) * 32 + c4 * 4]);
                        fma4(acc0, a0, w0);
                        fma4(acc0, a1, w1v);
                        fma4(acc0, a2, w2v);
                        fma4(acc1, a1, w0);
                        fma4(acc1, a2, w1v);
                        fma4(acc1, a3, w2v);
                    }
                }
                ushort4 s0, s1;
                s0.x = f2bf(fmaxf(acc0.x, 0.f)); s0.y = f2bf(fmaxf(acc0.y, 0.f));
                s0.z = f2bf(fmaxf(acc0.z, 0.f)); s0.w = f2bf(fmaxf(acc0.w, 0.f));
                s1.x = f2bf(fmaxf(acc1.x, 0.f)); s1.y = f2bf(fmaxf(acc1.y, 0.f));
                s1.z = f2bf(fmaxf(acc1.z, 0.f)); s1.w = f2bf(fmaxf(acc1.w, 0.f));
                unsigned char* dst = smem + row * LDS_STRIDE + xx * 64 + c4 * 8;
                *reinterpret_cast<ushort4*>(dst)      = s0;
                *reinterpret_cast<ushort4*>(dst + 64) = s1;
            }
        }
    }
    __syncthreads();   // A-tile published

    // ==== K-loop (r14 verbatim) ===========================================
    f32x4 acc[7][2];
    {
        const float bv0 = b2[nh * 32 + r];
        const float bv1 = b2[nh * 32 + 16 + r];
#pragma unroll
        for (int mt = 0; mt < 7; ++mt) {
            acc[mt][0] = (f32x4){bv0, bv0, bv0, bv0};
            acc[mt][1] = (f32x4){bv1, bv1, bv1, bv1};
        }
    }

    const unsigned char* aBase =
        smem + (zw * 6 + yl) * LDS_STRIDE + xg * 64 + q * 16;
    const char* wBl = (const char*)wB + nh * 2048 + l * 16;

    u32x4 Bs[3][2];
#define B_LOAD(slot, t)                                                        \
    { const char* p_ = wBl + (size_t)(t) * 4096;                               \
      asm volatile("global_load_dwordx4 %0, %2, off\n\t"                       \
                   "global_load_dwordx4 %1, %2, off offset:1024"               \
                   : "=&v"(Bs[slot][0]), "=&v"(Bs[slot][1]) : "v"(p_)); }

    B_LOAD(0, 0)
    B_LOAD(1, 1)

#pragma unroll
    for (int tap = 0; tap < 27; ++tap) {
        const int cur = tap % 3;

        if (tap < 25) B_LOAD((tap + 2) % 3, tap + 2)

        if (tap < 25)       asm volatile("s_waitcnt vmcnt(4)");
        else if (tap == 25) asm volatile("s_waitcnt vmcnt(2)");
        else                asm volatile("s_waitcnt vmcnt(0)");

        asm volatile("" : "+v"(Bs[cur][0]), "+v"(Bs[cur][1]));
        const bf16x8 B0 = __builtin_bit_cast(bf16x8, Bs[cur][0]);
        const bf16x8 B1 = __builtin_bit_cast(bf16x8, Bs[cur][1]);

        const int kd = tap / 9;
        const int kh = (tap - kd * 9) / 3;
        const int kw = tap - kd * 9 - kh * 3;
        const unsigned char* ap = aBase + (kd * 6 + kh) * LDS_STRIDE + kw * 64;

#pragma unroll
        for (int mt = 0; mt < 7; ++mt) {
            const bf16x8 a = *reinterpret_cast<const bf16x8*>(ap + mt * 256);
            acc[mt][0] = __builtin_amdgcn_mfma_f32_16x16x32_bf16(a, B0, acc[mt][0], 0, 0, 0);
            acc[mt][1] = __builtin_amdgcn_mfma_f32_16x16x32_bf16(a, B1, acc[mt][1], 0, 0, 0);
        }
    }
#undef B_LOAD

    // ==== epilogue: lane (r,q): co = nh*32+nt*16+r, y = y0+q, x = mt*4 ====
    const int z = z0 + zw;
    float* ob = out + ((size_t)b * 64 + nh * 32 + r) * OUT_CSTR
                    + (size_t)z * 784 + (size_t)(y0 + q) * 28;
#pragma unroll
    for (int mt = 0; mt < 7; ++mt) {
#pragma unroll
        for (int nt = 0; nt < 2; ++nt) {
            const f32x4 v = acc[mt][nt];
            float4 st;
            st.x = fmaxf(v.x, 0.f);
            st.y = fmaxf(v.y, 0.f);
            st.z = fmaxf(v.z, 0.f);
            st.w = fmaxf(v.w, 0.f);
            *reinterpret_cast<float4*>(ob + (size_t)nt * 16 * OUT_CSTR + mt * 4) = st;
        }
    }
}

extern "C" void kernel_launch(void* const* d_in, const int* in_sizes, int n_in,
                              void* d_out, int out_size, void* d_ws, size_t ws_size,
                              hipStream_t stream)
{
    const float* x  = (const float*)d_in[0];
    const float* w1 = (const float*)d_in[1];
    const float* b1 = (const float*)d_in[2];
    const float* w2 = (const float*)d_in[3];
    const float* b2 = (const float*)d_in[4];
    float* out = (float*)d_out;

    u16* wB = (u16*)d_ws;                               // 110,592 B packed weights

    pack_w2<<<27, 256, 0, stream>>>(w2, wB);
    conv2_fused<<<dim3(3136), 512, 0, stream>>>(x, w1, b1, wB, b2, out);
}

// Round 16
// 264.938 us; speedup vs baseline: 1.3405x; 1.3405x over previous
//
#include <hip/hip_runtime.h>
#include <cstdint>
#include <cstddef>

typedef __attribute__((ext_vector_type(8))) short bf16x8;
typedef __attribute__((ext_vector_type(4))) float f32x4;
typedef __attribute__((ext_vector_type(4))) unsigned int u32x4;
typedef unsigned short u16;

#define H1_ROW_B   1920                 /* packed row: 30x * 32ci * 2B     */
#define H1_BATCH   (30 * 30 * 960)      /* elems per batch (864000)        */
#define LDS_STRIDE 1952                 /* 1920 + 32: 488 dw = 8-bank row shift */
#define OUT_CSTR   21952                /* 28*28*28                        */

__device__ __forceinline__ u16 f2bf(float f) {
    union { float f; unsigned u; } v; v.f = f;
    unsigned r = v.u + 0x7FFF + ((v.u >> 16) & 1);   // RNE
    return (u16)(r >> 16);
}

__device__ __forceinline__ void fma4(float4& a, float s, const float4& w) {
    a.x = fmaf(s, w.x, a.x);
    a.y = fmaf(s, w.y, a.y);
    a.z = fmaf(s, w.z, a.z);
    a.w = fmaf(s, w.w, a.w);
}

__device__ __forceinline__ void gld_lds(const char* src, unsigned char* dst) {
    __builtin_amdgcn_global_load_lds(
        (const __attribute__((address_space(1))) void*)src,
        (__attribute__((address_space(3))) void*)dst, 16, 0, 0);
}

// ---------------- conv1 + bias + relu -> bf16 h1 [bl][z][y][30x][32ci] ----
// x-region staged in LDS (3 KB, one coalesced pass), weights in LDS, fully
// unrolled pair-blocked compute: all LDS reads + 648 FMAs in one ILP pool.
__global__ __launch_bounds__(256) void conv1_relu(
    const float* __restrict__ x, const float* __restrict__ w1,
    const float* __restrict__ b1, u16* __restrict__ h1, int b0)
{
    __shared__ float wl[27 * 32 + 32];
    __shared__ float xs[3 * 8 * 32];     // [zp][y][x] f32

    const int z   = blockIdx.x;        // 0..29
    const int yt  = blockIdx.y;        // 0..4
    const int bl  = blockIdx.z;
    const int b   = b0 + bl;
    const int tid = threadIdx.x;
    const int y0  = yt * 6;

    // stage x[z..z+2][y0..y0+7][0..31] (768 f32) : 192 threads x float4
    if (tid < 192) {
        const int idx = tid * 4;         // 0..764
        const int zp  = idx >> 8;        // /256
        const int rem = idx & 255;
        const int yy  = rem >> 5;
        const int xx  = rem & 31;
        xs[idx] = 0.f;  // placeholder overwritten below (keeps compiler honest)
        const float4 v = *reinterpret_cast<const float4*>(
            x + (size_t)b * 32768 + ((size_t)(z + zp) * 32 + (y0 + yy)) * 32 + xx);
        *reinterpret_cast<float4*>(&xs[idx]) = v;
    }
    for (int i = tid; i < 27 * 32; i += 256) wl[i] = w1[i];
    if (tid < 32) wl[27 * 32 + tid] = b1[tid];
    __syncthreads();

    const int c4   = tid & 7;          // ci c4*4 .. +3
    const int slot = tid >> 3;         // 0..31; active slots 0..29

    const float4 bias = *reinterpret_cast<const float4*>(&wl[27 * 32 + c4 * 4]);
    u16* h1b = h1 + (size_t)bl * H1_BATCH;

    if (slot < 30) {
#pragma unroll
        for (int j = 0; j < 3; ++j) {
            const int p  = slot + 30 * j;     // 0..89 pair index
            const int yy = p / 15;
            const int xx = (p - yy * 15) * 2; // 0,2,..,28
            const int y  = y0 + yy;

            float4 acc0 = bias, acc1 = bias;
#pragma unroll
            for (int kd = 0; kd < 3; ++kd) {
#pragma unroll
                for (int kh = 0; kh < 3; ++kh) {
                    const float* row = &xs[((kd * 8) + (yy + kh)) * 32 + xx];
                    const float2 v01 = *reinterpret_cast<const float2*>(row);
                    const float2 v23 = *reinterpret_cast<const float2*>(row + 2);
                    const int t = (kd * 3 + kh) * 3;
                    const float4 w0  = *reinterpret_cast<const float4*>(&wl[(t + 0) * 32 + c4 * 4]);
                    const float4 w1v = *reinterpret_cast<const float4*>(&wl[(t + 1) * 32 + c4 * 4]);
                    const float4 w2v = *reinterpret_cast<const float4*>(&wl[(t + 2) * 32 + c4 * 4]);
                    fma4(acc0, v01.x, w0);
                    fma4(acc0, v01.y, w1v);
                    fma4(acc0, v23.x, w2v);
                    fma4(acc1, v01.y, w0);
                    fma4(acc1, v23.x, w1v);
                    fma4(acc1, v23.y, w2v);
                }
            }
            ushort4 s0, s1;
            s0.x = f2bf(fmaxf(acc0.x, 0.f)); s0.y = f2bf(fmaxf(acc0.y, 0.f));
            s0.z = f2bf(fmaxf(acc0.z, 0.f)); s0.w = f2bf(fmaxf(acc0.w, 0.f));
            s1.x = f2bf(fmaxf(acc1.x, 0.f)); s1.y = f2bf(fmaxf(acc1.y, 0.f));
            s1.z = f2bf(fmaxf(acc1.z, 0.f)); s1.w = f2bf(fmaxf(acc1.w, 0.f));
            u16* dst = h1b + ((size_t)(z * 30 + y) * 30 + xx) * 32 + c4 * 4;
            *reinterpret_cast<ushort4*>(dst)      = s0;
            *reinterpret_cast<ushort4*>(dst + 32) = s1;
        }
    }
}

// ---------------- pack w2 fp32 DHWIO -> bf16 B-fragments ------------------
// wB[((tap*4 + nt)*64 + lane)*8 + j] = bf16(w2[tap][(lane>>4)*8 + j][nt*16 + (lane&15)])
__global__ __launch_bounds__(256) void pack_w2(
    const float* __restrict__ w2, u16* __restrict__ wB)
{
    const int tap = blockIdx.x;      // 0..26
    const int tid = threadIdx.x;
    const int nt = tid >> 6;
    const int l  = tid & 63;
    const int r = l & 15, q = l >> 4;
    u16* dst = wB + ((size_t)(tap * 4 + nt) * 64 + l) * 8;
#pragma unroll
    for (int j = 0; j < 8; ++j)
        dst[j] = f2bf(w2[(size_t)(tap * 32 + q * 8 + j) * 64 + nt * 16 + r]);
}

// ---------------- conv2 implicit-GEMM MFMA, 8-wave N-split (r14 verbatim) -
// Grid 49*bc x 512 thr (XCD-swizzled when %8==0). Block: 4z x 4y x 28x.
// 8 waves: wave wv -> z-plane zw=wv>>1, N-half nh=wv&1 (co nh*32..+31).
// Per wave: 7 m-tiles x 2 n-frags. A in LDS (36 x 1920 B, stride 1952,
// 0-conflict). B from global 2 KB/wave/tap, 2-deep prefetch, counted vmcnt.
// No setprio. 2 blocks/CU, 16 waves/CU. Best-measured config (r9/r14).
__global__ __launch_bounds__(512, 4) void conv2_mfma(
    const u16* __restrict__ h1, const u16* __restrict__ wB,
    const float* __restrict__ b2, float* __restrict__ out, int b0)
{
    __shared__ __align__(16) unsigned char smem[36 * LDS_STRIDE];  // 70272 B

    const int g   = gridDim.x;
    const int bid = blockIdx.x;
    const int lb  = (g % 8 == 0) ? ((bid & 7) * (g >> 3) + (bid >> 3)) : bid;

    const int t0  = lb % 49;
    const int bl  = lb / 49;
    const int yg  = t0 % 7;
    const int zt  = t0 / 7;

    const int b  = b0 + bl;
    const int y0 = yg * 4, z0 = zt * 4;
    const int tid = threadIdx.x;
    const int wv  = tid >> 6;       // 0..7
    const int l   = tid & 63;
    const int zw  = wv >> 1;        // wave z offset 0..3
    const int nh  = wv & 1;         // wave N half
    const int r = l & 15, q = l >> 4;
    const int yl = r >> 2, xg = r & 3;

    const char* wBl = (const char*)wB + nh * 2048 + l * 16;

    // ---- stage A: 36 rows x 1920 B, chunks at 0 and 896 (128 B overlap) --
    {
        const char* gbase = (const char*)(h1 + (size_t)bl * H1_BATCH);
        for (int c = wv; c < 72; c += 8) {           // wave-uniform chunks
            const int rid = c >> 1, half = c & 1;
            const int zz = rid / 6, yy = rid - zz * 6;
            const char* src = gbase
                + (size_t)((z0 + zz) * 30 + (y0 + yy)) * H1_ROW_B
                + half * 896 + l * 16;
            unsigned char* dst = smem + rid * LDS_STRIDE + half * 896 + l * 16;
            gld_lds(src, dst);
        }
    }
    __syncthreads();   // drains staging (vmcnt(0)) + publishes LDS

    // ---- accumulators init with bias (co = nh*32 + nt*16 + r) ----
    f32x4 acc[7][2];
    {
        const float bv0 = b2[nh * 32 + r];
        const float bv1 = b2[nh * 32 + 16 + r];
#pragma unroll
        for (int mt = 0; mt < 7; ++mt) {
            acc[mt][0] = (f32x4){bv0, bv0, bv0, bv0};
            acc[mt][1] = (f32x4){bv1, bv1, bv1, bv1};
        }
    }

    // per-lane A base: row (zw+kd)*6 + (yl+kh), x = mt*4 + xg + kw, K-qtr q
    const unsigned char* aBase =
        smem + (zw * 6 + yl) * LDS_STRIDE + xg * 64 + q * 16;

    u32x4 Bs[3][2];
#define B_LOAD(slot, t)                                                        \
    { const char* p_ = wBl + (size_t)(t) * 4096;                               \
      asm volatile("global_load_dwordx4 %0, %2, off\n\t"                       \
                   "global_load_dwordx4 %1, %2, off offset:1024"               \
                   : "=&v"(Bs[slot][0]), "=&v"(Bs[slot][1]) : "v"(p_)); }

    // 2-deep prologue (staging already drained -> vmcnt counting exact)
    B_LOAD(0, 0)
    B_LOAD(1, 1)

    // ---- barrier-free K-loop over 27 taps, fully unrolled ----
#pragma unroll
    for (int tap = 0; tap < 27; ++tap) {
        const int cur = tap % 3;

        if (tap < 25) B_LOAD((tap + 2) % 3, tap + 2)

        // after wait: taps t+1 (and t+2 if issued) remain in flight
        if (tap < 25)       asm volatile("s_waitcnt vmcnt(4)");
        else if (tap == 25) asm volatile("s_waitcnt vmcnt(2)");
        else                asm volatile("s_waitcnt vmcnt(0)");

        asm volatile("" : "+v"(Bs[cur][0]), "+v"(Bs[cur][1]));
        const bf16x8 B0 = __builtin_bit_cast(bf16x8, Bs[cur][0]);
        const bf16x8 B1 = __builtin_bit_cast(bf16x8, Bs[cur][1]);

        const int kd = tap / 9;
        const int kh = (tap - kd * 9) / 3;
        const int kw = tap - kd * 9 - kh * 3;
        const unsigned char* ap = aBase + (kd * 6 + kh) * LDS_STRIDE + kw * 64;

#pragma unroll
        for (int mt = 0; mt < 7; ++mt) {
            const bf16x8 a = *reinterpret_cast<const bf16x8*>(ap + mt * 256);
            acc[mt][0] = __builtin_amdgcn_mfma_f32_16x16x32_bf16(a, B0, acc[mt][0], 0, 0, 0);
            acc[mt][1] = __builtin_amdgcn_mfma_f32_16x16x32_bf16(a, B1, acc[mt][1], 0, 0, 0);
        }
    }
#undef B_LOAD

    // ---- epilogue: lane (r,q): co = nh*32+nt*16+r, y = y0+q, x = mt*4 (+j)
    const int z = z0 + zw;
    float* ob = out + ((size_t)b * 64 + nh * 32 + r) * OUT_CSTR
                    + (size_t)z * 784 + (size_t)(y0 + q) * 28;
#pragma unroll
    for (int mt = 0; mt < 7; ++mt) {
#pragma unroll
        for (int nt = 0; nt < 2; ++nt) {
            const f32x4 v = acc[mt][nt];
            float4 st;
            st.x = fmaxf(v.x, 0.f);
            st.y = fmaxf(v.y, 0.f);
            st.z = fmaxf(v.z, 0.f);
            st.w = fmaxf(v.w, 0.f);
            *reinterpret_cast<float4*>(ob + (size_t)nt * 16 * OUT_CSTR + mt * 4) = st;
        }
    }
}

extern "C" void kernel_launch(void* const* d_in, const int* in_sizes, int n_in,
                              void* d_out, int out_size, void* d_ws, size_t ws_size,
                              hipStream_t stream)
{
    const float* x  = (const float*)d_in[0];
    const float* w1 = (const float*)d_in[1];
    const float* b1 = (const float*)d_in[2];
    const float* w2 = (const float*)d_in[3];
    const float* b2 = (const float*)d_in[4];
    float* out = (float*)d_out;

    u16* wB = (u16*)d_ws;                               // 110,592 B packed weights
    u16* h1 = (u16*)((char*)d_ws + 131072);

    pack_w2<<<27, 256, 0, stream>>>(w2, wB);

    const size_t per_batch = (size_t)H1_BATCH * 2;      // 1,728,000 B
    size_t avail = ws_size > 131072 ? ws_size - 131072 : 0;
    int bchunk = (int)(avail / per_batch);
    if (bchunk < 1)  bchunk = 1;
    if (bchunk > 64) bchunk = 64;

    for (int b0 = 0; b0 < 64; b0 += bchunk) {
        int bc = 64 - b0;
        if (bc > bchunk) bc = bchunk;
        conv1_relu<<<dim3(30, 5, bc), 256, 0, stream>>>(x, w1, b1, h1, b0);
        conv2_mfma<<<dim3(49 * bc), 512, 0, stream>>>(h1, wB, b2, out, b0);
    }
}

// Round 17
// 255.845 us; speedup vs baseline: 1.3882x; 1.0355x over previous
//
#include <hip/hip_runtime.h>
#include <cstdint>
#include <cstddef>

typedef __attribute__((ext_vector_type(8))) short bf16x8;
typedef __attribute__((ext_vector_type(4))) float f32x4;
typedef __attribute__((ext_vector_type(4))) unsigned int u32x4;
typedef unsigned short u16;

#define H1_ROW_B   1920                 /* packed row: 30x * 32ci * 2B     */
#define H1_BATCH   (30 * 30 * 960)      /* elems per batch (864000)        */
#define LDS_STRIDE 1952                 /* 1920 + 32: 488 dw = 8-bank row shift */
#define OUT_CSTR   21952                /* 28*28*28                        */

__device__ __forceinline__ u16 f2bf(float f) {
    union { float f; unsigned u; } v; v.f = f;
    unsigned r = v.u + 0x7FFF + ((v.u >> 16) & 1);   // RNE
    return (u16)(r >> 16);
}

__device__ __forceinline__ void fma4(float4& a, float s, const float4& w) {
    a.x = fmaf(s, w.x, a.x);
    a.y = fmaf(s, w.y, a.y);
    a.z = fmaf(s, w.z, a.z);
    a.w = fmaf(s, w.w, a.w);
}

__device__ __forceinline__ void gld_lds(const char* src, unsigned char* dst) {
    __builtin_amdgcn_global_load_lds(
        (const __attribute__((address_space(1))) void*)src,
        (__attribute__((address_space(3))) void*)dst, 16, 0, 0);
}

// ---------------- conv1 + bias + relu -> bf16 h1 [bl][z][y][30x][32ci] ----
// x staged in LDS (one coalesced pass); WEIGHTS IN REGISTERS (27 x float4
// from global, same addrs across waves -> L1 broadcast). This removes the
// 81 ds_read_b128/thread weight reads that made r16's conv1 LDS-bound.
__global__ __launch_bounds__(256) void conv1_relu(
    const float* __restrict__ x, const float* __restrict__ w1,
    const float* __restrict__ b1, u16* __restrict__ h1, int b0)
{
    __shared__ float xs[3 * 8 * 32];     // [zp][y][x] f32, 3 KB

    const int z   = blockIdx.x;        // 0..29
    const int yt  = blockIdx.y;        // 0..4
    const int bl  = blockIdx.z;
    const int b   = b0 + bl;
    const int tid = threadIdx.x;
    const int y0  = yt * 6;

    // stage x[z..z+2][y0..y0+7][0..31] (768 f32) : 192 threads x float4
    if (tid < 192) {
        const int idx = tid * 4;         // 0..764
        const int zp  = idx >> 8;
        const int rem = idx & 255;
        const int yy  = rem >> 5;
        const int xx  = rem & 31;
        const float4 v = *reinterpret_cast<const float4*>(
            x + (size_t)b * 32768 + ((size_t)(z + zp) * 32 + (y0 + yy)) * 32 + xx);
        *reinterpret_cast<float4*>(&xs[idx]) = v;
    }

    const int c4   = tid & 7;          // ci c4*4 .. +3
    const int slot = tid >> 3;         // 0..31; active slots 0..29

    // weights -> registers (L1-broadcast: all waves read the same 3.5 KB)
    float4 wr[27];
#pragma unroll
    for (int t = 0; t < 27; ++t)
        wr[t] = *reinterpret_cast<const float4*>(w1 + t * 32 + c4 * 4);
    const float4 bias = *reinterpret_cast<const float4*>(b1 + c4 * 4);

    __syncthreads();

    u16* h1b = h1 + (size_t)bl * H1_BATCH;

    if (slot < 30) {
#pragma unroll
        for (int j = 0; j < 3; ++j) {
            const int p  = slot + 30 * j;     // 0..89 pair index
            const int yy = p / 15;
            const int xx = (p - yy * 15) * 2; // 0,2,..,28 (8B aligned)
            const int y  = y0 + yy;

            float4 acc0 = bias, acc1 = bias;
#pragma unroll
            for (int kd = 0; kd < 3; ++kd) {
#pragma unroll
                for (int kh = 0; kh < 3; ++kh) {
                    const float* row = &xs[((kd * 8) + (yy + kh)) * 32 + xx];
                    const float2 v01 = *reinterpret_cast<const float2*>(row);
                    const float2 v23 = *reinterpret_cast<const float2*>(row + 2);
                    const int t = (kd * 3 + kh) * 3;
                    fma4(acc0, v01.x, wr[t + 0]);
                    fma4(acc0, v01.y, wr[t + 1]);
                    fma4(acc0, v23.x, wr[t + 2]);
                    fma4(acc1, v01.y, wr[t + 0]);
                    fma4(acc1, v23.x, wr[t + 1]);
                    fma4(acc1, v23.y, wr[t + 2]);
                }
            }
            ushort4 s0, s1;
            s0.x = f2bf(fmaxf(acc0.x, 0.f)); s0.y = f2bf(fmaxf(acc0.y, 0.f));
            s0.z = f2bf(fmaxf(acc0.z, 0.f)); s0.w = f2bf(fmaxf(acc0.w, 0.f));
            s1.x = f2bf(fmaxf(acc1.x, 0.f)); s1.y = f2bf(fmaxf(acc1.y, 0.f));
            s1.z = f2bf(fmaxf(acc1.z, 0.f)); s1.w = f2bf(fmaxf(acc1.w, 0.f));
            u16* dst = h1b + ((size_t)(z * 30 + y) * 30 + xx) * 32 + c4 * 4;
            *reinterpret_cast<ushort4*>(dst)      = s0;
            *reinterpret_cast<ushort4*>(dst + 32) = s1;
        }
    }
}

// ---------------- pack w2 fp32 DHWIO -> bf16 B-fragments ------------------
// wB[((tap*4 + nt)*64 + lane)*8 + j] = bf16(w2[tap][(lane>>4)*8 + j][nt*16 + (lane&15)])
__global__ __launch_bounds__(256) void pack_w2(
    const float* __restrict__ w2, u16* __restrict__ wB)
{
    const int tap = blockIdx.x;      // 0..26
    const int tid = threadIdx.x;
    const int nt = tid >> 6;
    const int l  = tid & 63;
    const int r = l & 15, q = l >> 4;
    u16* dst = wB + ((size_t)(tap * 4 + nt) * 64 + l) * 8;
#pragma unroll
    for (int j = 0; j < 8; ++j)
        dst[j] = f2bf(w2[(size_t)(tap * 32 + q * 8 + j) * 64 + nt * 16 + r]);
}

// ---------------- conv2 implicit-GEMM MFMA, 8-wave N-split (r14 verbatim) -
// Grid 49*bc x 512 thr (XCD-swizzled when %8==0). Block: 4z x 4y x 28x.
// 8 waves: wave wv -> z-plane zw=wv>>1, N-half nh=wv&1 (co nh*32..+31).
// Per wave: 7 m-tiles x 2 n-frags. A in LDS (36 x 1920 B, stride 1952,
// 0-conflict). B from global 2 KB/wave/tap, 2-deep prefetch, counted vmcnt.
// No setprio. 2 blocks/CU, 16 waves/CU. Best-measured config (r9/r14).
__global__ __launch_bounds__(512, 4) void conv2_mfma(
    const u16* __restrict__ h1, const u16* __restrict__ wB,
    const float* __restrict__ b2, float* __restrict__ out, int b0)
{
    __shared__ __align__(16) unsigned char smem[36 * LDS_STRIDE];  // 70272 B

    const int g   = gridDim.x;
    const int bid = blockIdx.x;
    const int lb  = (g % 8 == 0) ? ((bid & 7) * (g >> 3) + (bid >> 3)) : bid;

    const int t0  = lb % 49;
    const int bl  = lb / 49;
    const int yg  = t0 % 7;
    const int zt  = t0 / 7;

    const int b  = b0 + bl;
    const int y0 = yg * 4, z0 = zt * 4;
    const int tid = threadIdx.x;
    const int wv  = tid >> 6;       // 0..7
    const int l   = tid & 63;
    const int zw  = wv >> 1;        // wave z offset 0..3
    const int nh  = wv & 1;         // wave N half
    const int r = l & 15, q = l >> 4;
    const int yl = r >> 2, xg = r & 3;

    const char* wBl = (const char*)wB + nh * 2048 + l * 16;

    // ---- stage A: 36 rows x 1920 B, chunks at 0 and 896 (128 B overlap) --
    {
        const char* gbase = (const char*)(h1 + (size_t)bl * H1_BATCH);
        for (int c = wv; c < 72; c += 8) {           // wave-uniform chunks
            const int rid = c >> 1, half = c & 1;
            const int zz = rid / 6, yy = rid - zz * 6;
            const char* src = gbase
                + (size_t)((z0 + zz) * 30 + (y0 + yy)) * H1_ROW_B
                + half * 896 + l * 16;
            unsigned char* dst = smem + rid * LDS_STRIDE + half * 896 + l * 16;
            gld_lds(src, dst);
        }
    }
    __syncthreads();   // drains staging (vmcnt(0)) + publishes LDS

    // ---- accumulators init with bias (co = nh*32 + nt*16 + r) ----
    f32x4 acc[7][2];
    {
        const float bv0 = b2[nh * 32 + r];
        const float bv1 = b2[nh * 32 + 16 + r];
#pragma unroll
        for (int mt = 0; mt < 7; ++mt) {
            acc[mt][0] = (f32x4){bv0, bv0, bv0, bv0};
            acc[mt][1] = (f32x4){bv1, bv1, bv1, bv1};
        }
    }

    // per-lane A base: row (zw+kd)*6 + (yl+kh), x = mt*4 + xg + kw, K-qtr q
    const unsigned char* aBase =
        smem + (zw * 6 + yl) * LDS_STRIDE + xg * 64 + q * 16;

    u32x4 Bs[3][2];
#define B_LOAD(slot, t)                                                        \
    { const char* p_ = wBl + (size_t)(t) * 4096;                               \
      asm volatile("global_load_dwordx4 %0, %2, off\n\t"                       \
                   "global_load_dwordx4 %1, %2, off offset:1024"               \
                   : "=&v"(Bs[slot][0]), "=&v"(Bs[slot][1]) : "v"(p_)); }

    // 2-deep prologue (staging already drained -> vmcnt counting exact)
    B_LOAD(0, 0)
    B_LOAD(1, 1)

    // ---- barrier-free K-loop over 27 taps, fully unrolled ----
#pragma unroll
    for (int tap = 0; tap < 27; ++tap) {
        const int cur = tap % 3;

        if (tap < 25) B_LOAD((tap + 2) % 3, tap + 2)

        // after wait: taps t+1 (and t+2 if issued) remain in flight
        if (tap < 25)       asm volatile("s_waitcnt vmcnt(4)");
        else if (tap == 25) asm volatile("s_waitcnt vmcnt(2)");
        else                asm volatile("s_waitcnt vmcnt(0)");

        asm volatile("" : "+v"(Bs[cur][0]), "+v"(Bs[cur][1]));
        const bf16x8 B0 = __builtin_bit_cast(bf16x8, Bs[cur][0]);
        const bf16x8 B1 = __builtin_bit_cast(bf16x8, Bs[cur][1]);

        const int kd = tap / 9;
        const int kh = (tap - kd * 9) / 3;
        const int kw = tap - kd * 9 - kh * 3;
        const unsigned char* ap = aBase + (kd * 6 + kh) * LDS_STRIDE + kw * 64;

#pragma unroll
        for (int mt = 0; mt < 7; ++mt) {
            const bf16x8 a = *reinterpret_cast<const bf16x8*>(ap + mt * 256);
            acc[mt][0] = __builtin_amdgcn_mfma_f32_16x16x32_bf16(a, B0, acc[mt][0], 0, 0, 0);
            acc[mt][1] = __builtin_amdgcn_mfma_f32_16x16x32_bf16(a, B1, acc[mt][1], 0, 0, 0);
        }
    }
#undef B_LOAD

    // ---- epilogue: lane (r,q): co = nh*32+nt*16+r, y = y0+q, x = mt*4 (+j)
    const int z = z0 + zw;
    float* ob = out + ((size_t)b * 64 + nh * 32 + r) * OUT_CSTR
                    + (size_t)z * 784 + (size_t)(y0 + q) * 28;
#pragma unroll
    for (int mt = 0; mt < 7; ++mt) {
#pragma unroll
        for (int nt = 0; nt < 2; ++nt) {
            const f32x4 v = acc[mt][nt];
            float4 st;
            st.x = fmaxf(v.x, 0.f);
            st.y = fmaxf(v.y, 0.f);
            st.z = fmaxf(v.z, 0.f);
            st.w = fmaxf(v.w, 0.f);
            *reinterpret_cast<float4*>(ob + (size_t)nt * 16 * OUT_CSTR + mt * 4) = st;
        }
    }
}

extern "C" void kernel_launch(void* const* d_in, const int* in_sizes, int n_in,
                              void* d_out, int out_size, void* d_ws, size_t ws_size,
                              hipStream_t stream)
{
    const float* x  = (const float*)d_in[0];
    const float* w1 = (const float*)d_in[1];
    const float* b1 = (const float*)d_in[2];
    const float* w2 = (const float*)d_in[3];
    const float* b2 = (const float*)d_in[4];
    float* out = (float*)d_out;

    u16* wB = (u16*)d_ws;                               // 110,592 B packed weights
    u16* h1 = (u16*)((char*)d_ws + 131072);

    pack_w2<<<27, 256, 0, stream>>>(w2, wB);

    const size_t per_batch = (size_t)H1_BATCH * 2;      // 1,728,000 B
    size_t avail = ws_size > 131072 ? ws_size - 131072 : 0;
    int bchunk = (int)(avail / per_batch);
    if (bchunk < 1)  bchunk = 1;
    if (bchunk > 64) bchunk = 64;

    for (int b0 = 0; b0 < 64; b0 += bchunk) {
        int bc = 64 - b0;
        if (bc > bchunk) bc = bchunk;
        conv1_relu<<<dim3(30, 5, bc), 256, 0, stream>>>(x, w1, b1, h1, b0);
        conv2_mfma<<<dim3(49 * bc), 512, 0, stream>>>(h1, wB, b2, out, b0);
    }
}

// Round 18
// 254.020 us; speedup vs baseline: 1.3981x; 1.0072x over previous
//
#include <hip/hip_runtime.h>
#include <cstdint>
#include <cstddef>

typedef __attribute__((ext_vector_type(8))) short bf16x8;
typedef __attribute__((ext_vector_type(4))) float f32x4;
typedef __attribute__((ext_vector_type(4))) unsigned int u32x4;
typedef unsigned short u16;

#define H1_ROW_B   1920                 /* packed row: 30x * 32ci * 2B     */
#define H1_BATCH   (30 * 30 * 960)      /* elems per batch (864000)        */
#define LDS_STRIDE 1952                 /* 1920 + 32: 488 dw = 8-bank row shift */
#define OUT_CSTR   21952                /* 28*28*28                        */

__device__ __forceinline__ u16 f2bf(float f) {
    union { float f; unsigned u; } v; v.f = f;
    unsigned r = v.u + 0x7FFF + ((v.u >> 16) & 1);   // RNE
    return (u16)(r >> 16);
}

__device__ __forceinline__ void fma4(float4& a, float s, const float4& w) {
    a.x = fmaf(s, w.x, a.x);
    a.y = fmaf(s, w.y, a.y);
    a.z = fmaf(s, w.z, a.z);
    a.w = fmaf(s, w.w, a.w);
}

__device__ __forceinline__ void gld_lds(const char* src, unsigned char* dst) {
    __builtin_amdgcn_global_load_lds(
        (const __attribute__((address_space(1))) void*)src,
        (__attribute__((address_space(3))) void*)dst, 16, 0, 0);
}

// ---------------- conv1 + bias + relu -> bf16 h1 [bl][z][y][30x][32ci] ----
// x staged in LDS (one coalesced pass); weights in registers (L1-broadcast).
__global__ __launch_bounds__(256) void conv1_relu(
    const float* __restrict__ x, const float* __restrict__ w1,
    const float* __restrict__ b1, u16* __restrict__ h1, int b0)
{
    __shared__ float xs[3 * 8 * 32];     // [zp][y][x] f32, 3 KB

    const int z   = blockIdx.x;        // 0..29
    const int yt  = blockIdx.y;        // 0..4
    const int bl  = blockIdx.z;
    const int b   = b0 + bl;
    const int tid = threadIdx.x;
    const int y0  = yt * 6;

    // stage x[z..z+2][y0..y0+7][0..31] (768 f32) : 192 threads x float4
    if (tid < 192) {
        const int idx = tid * 4;         // 0..764
        const int zp  = idx >> 8;
        const int rem = idx & 255;
        const int yy  = rem >> 5;
        const int xx  = rem & 31;
        const float4 v = *reinterpret_cast<const float4*>(
            x + (size_t)b * 32768 + ((size_t)(z + zp) * 32 + (y0 + yy)) * 32 + xx);
        *reinterpret_cast<float4*>(&xs[idx]) = v;
    }

    const int c4   = tid & 7;          // ci c4*4 .. +3
    const int slot = tid >> 3;         // 0..31; active slots 0..29

    // weights -> registers (L1-broadcast: all waves read the same 3.5 KB)
    float4 wr[27];
#pragma unroll
    for (int t = 0; t < 27; ++t)
        wr[t] = *reinterpret_cast<const float4*>(w1 + t * 32 + c4 * 4);
    const float4 bias = *reinterpret_cast<const float4*>(b1 + c4 * 4);

    __syncthreads();

    u16* h1b = h1 + (size_t)bl * H1_BATCH;

    if (slot < 30) {
#pragma unroll
        for (int j = 0; j < 3; ++j) {
            const int p  = slot + 30 * j;     // 0..89 pair index
            const int yy = p / 15;
            const int xx = (p - yy * 15) * 2; // 0,2,..,28 (8B aligned)
            const int y  = y0 + yy;

            float4 acc0 = bias, acc1 = bias;
#pragma unroll
            for (int kd = 0; kd < 3; ++kd) {
#pragma unroll
                for (int kh = 0; kh < 3; ++kh) {
                    const float* row = &xs[((kd * 8) + (yy + kh)) * 32 + xx];
                    const float2 v01 = *reinterpret_cast<const float2*>(row);
                    const float2 v23 = *reinterpret_cast<const float2*>(row + 2);
                    const int t = (kd * 3 + kh) * 3;
                    fma4(acc0, v01.x, wr[t + 0]);
                    fma4(acc0, v01.y, wr[t + 1]);
                    fma4(acc0, v23.x, wr[t + 2]);
                    fma4(acc1, v01.y, wr[t + 0]);
                    fma4(acc1, v23.x, wr[t + 1]);
                    fma4(acc1, v23.y, wr[t + 2]);
                }
            }
            ushort4 s0, s1;
            s0.x = f2bf(fmaxf(acc0.x, 0.f)); s0.y = f2bf(fmaxf(acc0.y, 0.f));
            s0.z = f2bf(fmaxf(acc0.z, 0.f)); s0.w = f2bf(fmaxf(acc0.w, 0.f));
            s1.x = f2bf(fmaxf(acc1.x, 0.f)); s1.y = f2bf(fmaxf(acc1.y, 0.f));
            s1.z = f2bf(fmaxf(acc1.z, 0.f)); s1.w = f2bf(fmaxf(acc1.w, 0.f));
            u16* dst = h1b + ((size_t)(z * 30 + y) * 30 + xx) * 32 + c4 * 4;
            *reinterpret_cast<ushort4*>(dst)      = s0;
            *reinterpret_cast<ushort4*>(dst + 32) = s1;
        }
    }
}

// ---------------- pack w2 fp32 DHWIO -> bf16 B-fragments ------------------
// wB[((tap*4 + nt)*64 + lane)*8 + j] = bf16(w2[tap][(lane>>4)*8 + j][nt*16 + (lane&15)])
__global__ __launch_bounds__(256) void pack_w2(
    const float* __restrict__ w2, u16* __restrict__ wB)
{
    const int tap = blockIdx.x;      // 0..26
    const int tid = threadIdx.x;
    const int nt = tid >> 6;
    const int l  = tid & 63;
    const int r = l & 15, q = l >> 4;
    u16* dst = wB + ((size_t)(tap * 4 + nt) * 64 + l) * 8;
#pragma unroll
    for (int j = 0; j < 8; ++j)
        dst[j] = f2bf(w2[(size_t)(tap * 32 + q * 8 + j) * 64 + nt * 16 + r]);
}

// ---------------- conv2 implicit-GEMM MFMA, 8-wave N-split ----------------
// r14-verbatim K-loop (best measured). Epilogue reordered nt-outer/mt-inner:
// each lane's 7 16B stores are address-consecutive (112 B contiguous run)
// -> L2 write-combining merges full lines (WRITE_SIZE 1.3x -> ~1.05x).
__global__ __launch_bounds__(512, 4) void conv2_mfma(
    const u16* __restrict__ h1, const u16* __restrict__ wB,
    const float* __restrict__ b2, float* __restrict__ out, int b0)
{
    __shared__ __align__(16) unsigned char smem[36 * LDS_STRIDE];  // 70272 B

    const int g   = gridDim.x;
    const int bid = blockIdx.x;
    const int lb  = (g % 8 == 0) ? ((bid & 7) * (g >> 3) + (bid >> 3)) : bid;

    const int t0  = lb % 49;
    const int bl  = lb / 49;
    const int yg  = t0 % 7;
    const int zt  = t0 / 7;

    const int b  = b0 + bl;
    const int y0 = yg * 4, z0 = zt * 4;
    const int tid = threadIdx.x;
    const int wv  = tid >> 6;       // 0..7
    const int l   = tid & 63;
    const int zw  = wv >> 1;        // wave z offset 0..3
    const int nh  = wv & 1;         // wave N half
    const int r = l & 15, q = l >> 4;
    const int yl = r >> 2, xg = r & 3;

    const char* wBl = (const char*)wB + nh * 2048 + l * 16;

    // ---- stage A: 36 rows x 1920 B, chunks at 0 and 896 (128 B overlap) --
    {
        const char* gbase = (const char*)(h1 + (size_t)bl * H1_BATCH);
        for (int c = wv; c < 72; c += 8) {           // wave-uniform chunks
            const int rid = c >> 1, half = c & 1;
            const int zz = rid / 6, yy = rid - zz * 6;
            const char* src = gbase
                + (size_t)((z0 + zz) * 30 + (y0 + yy)) * H1_ROW_B
                + half * 896 + l * 16;
            unsigned char* dst = smem + rid * LDS_STRIDE + half * 896 + l * 16;
            gld_lds(src, dst);
        }
    }
    __syncthreads();   // drains staging (vmcnt(0)) + publishes LDS

    // ---- accumulators init with bias (co = nh*32 + nt*16 + r) ----
    f32x4 acc[7][2];
    {
        const float bv0 = b2[nh * 32 + r];
        const float bv1 = b2[nh * 32 + 16 + r];
#pragma unroll
        for (int mt = 0; mt < 7; ++mt) {
            acc[mt][0] = (f32x4){bv0, bv0, bv0, bv0};
            acc[mt][1] = (f32x4){bv1, bv1, bv1, bv1};
        }
    }

    // per-lane A base: row (zw+kd)*6 + (yl+kh), x = mt*4 + xg + kw, K-qtr q
    const unsigned char* aBase =
        smem + (zw * 6 + yl) * LDS_STRIDE + xg * 64 + q * 16;

    u32x4 Bs[3][2];
#define B_LOAD(slot, t)                                                        \
    { const char* p_ = wBl + (size_t)(t) * 4096;                               \
      asm volatile("global_load_dwordx4 %0, %2, off\n\t"                       \
                   "global_load_dwordx4 %1, %2, off offset:1024"               \
                   : "=&v"(Bs[slot][0]), "=&v"(Bs[slot][1]) : "v"(p_)); }

    // 2-deep prologue (staging already drained -> vmcnt counting exact)
    B_LOAD(0, 0)
    B_LOAD(1, 1)

    // ---- barrier-free K-loop over 27 taps, fully unrolled ----
#pragma unroll
    for (int tap = 0; tap < 27; ++tap) {
        const int cur = tap % 3;

        if (tap < 25) B_LOAD((tap + 2) % 3, tap + 2)

        // after wait: taps t+1 (and t+2 if issued) remain in flight
        if (tap < 25)       asm volatile("s_waitcnt vmcnt(4)");
        else if (tap == 25) asm volatile("s_waitcnt vmcnt(2)");
        else                asm volatile("s_waitcnt vmcnt(0)");

        asm volatile("" : "+v"(Bs[cur][0]), "+v"(Bs[cur][1]));
        const bf16x8 B0 = __builtin_bit_cast(bf16x8, Bs[cur][0]);
        const bf16x8 B1 = __builtin_bit_cast(bf16x8, Bs[cur][1]);

        const int kd = tap / 9;
        const int kh = (tap - kd * 9) / 3;
        const int kw = tap - kd * 9 - kh * 3;
        const unsigned char* ap = aBase + (kd * 6 + kh) * LDS_STRIDE + kw * 64;

#pragma unroll
        for (int mt = 0; mt < 7; ++mt) {
            const bf16x8 a = *reinterpret_cast<const bf16x8*>(ap + mt * 256);
            acc[mt][0] = __builtin_amdgcn_mfma_f32_16x16x32_bf16(a, B0, acc[mt][0], 0, 0, 0);
            acc[mt][1] = __builtin_amdgcn_mfma_f32_16x16x32_bf16(a, B1, acc[mt][1], 0, 0, 0);
        }
    }
#undef B_LOAD

    // ---- epilogue (nt OUTER, mt INNER): lane (r,q): co = nh*32+nt*16+r,
    // y = y0+q, x = mt*4..+3 — 7 consecutive 16B stores per lane = 112 B run
    const int z = z0 + zw;
    float* ob = out + ((size_t)b * 64 + nh * 32 + r) * OUT_CSTR
                    + (size_t)z * 784 + (size_t)(y0 + q) * 28;
#pragma unroll
    for (int nt = 0; nt < 2; ++nt) {
        float* obn = ob + (size_t)nt * 16 * OUT_CSTR;
#pragma unroll
        for (int mt = 0; mt < 7; ++mt) {
            const f32x4 v = acc[mt][nt];
            float4 st;
            st.x = fmaxf(v.x, 0.f);
            st.y = fmaxf(v.y, 0.f);
            st.z = fmaxf(v.z, 0.f);
            st.w = fmaxf(v.w, 0.f);
            *reinterpret_cast<float4*>(obn + mt * 4) = st;
        }
    }
}

extern "C" void kernel_launch(void* const* d_in, const int* in_sizes, int n_in,
                              void* d_out, int out_size, void* d_ws, size_t ws_size,
                              hipStream_t stream)
{
    const float* x  = (const float*)d_in[0];
    const float* w1 = (const float*)d_in[1];
    const float* b1 = (const float*)d_in[2];
    const float* w2 = (const float*)d_in[3];
    const float* b2 = (const float*)d_in[4];
    float* out = (float*)d_out;

    u16* wB = (u16*)d_ws;                               // 110,592 B packed weights
    u16* h1 = (u16*)((char*)d_ws + 131072);

    pack_w2<<<27, 256, 0, stream>>>(w2, wB);

    const size_t per_batch = (size_t)H1_BATCH * 2;      // 1,728,000 B
    size_t avail = ws_size > 131072 ? ws_size - 131072 : 0;
    int bchunk = (int)(avail / per_batch);
    if (bchunk < 1)  bchunk = 1;
    if (bchunk > 64) bchunk = 64;

    for (int b0 = 0; b0 < 64; b0 += bchunk) {
        int bc = 64 - b0;
        if (bc > bchunk) bc = bchunk;
        conv1_relu<<<dim3(30, 5, bc), 256, 0, stream>>>(x, w1, b1, h1, b0);
        conv2_mfma<<<dim3(49 * bc), 512, 0, stream>>>(h1, wB, b2, out, b0);
    }
}